// Round 2
// baseline (111.954 us; speedup 1.0000x reference)
//
#include <hip/hip_runtime.h>

// PixelEffectModule: 8-bin intensity histogram over 11x11 windows at stride 8,
// pick argmax bin, output that bin's mean RGB, upsampled 8x8.
// Input:  rgb (1,3,2048,2048) fp32 in [0,255). Output: (1,3,2048,2048) fp32.
//
// Parallelization: 4 threads (a lane-quad) per output cell. Window rows split
// 3/3/3/2 across the quad. Counts packed as 8x u8 in a u64, reduced with
// __shfl_xor; argmax; second pass re-reads (L1/L2-hot) summing only the
// winning bin's r,g,b.

#define H 2048
#define W 2048
#define NB 8
#define K 11
#define PAD 5
#define PS 8
#define OH 256
#define OW 256
#define HW (H * W)

// correctly-rounded t/3 (Markstein 2-fma refinement) — matches v_div bits,
// 3 ops instead of the ~9-inst precise-division expansion.
__device__ __forceinline__ float div3(float t) {
    const float c = 0x1.555556p-2f;  // RN(1/3)
    float q0 = t * c;
    float r  = __builtin_fmaf(q0, -3.0f, t);
    return __builtin_fmaf(r, c, q0);
}

__device__ __forceinline__ float fget(const float4* V, int j) {
    return ((const float*)V)[j];  // j is compile-time in unrolled loops
}

__device__ __forceinline__ void load_row(const float* base, float4* V, bool left) {
    const float4* q = (const float4*)base;
    if (!left) { V[0] = q[0]; V[1] = q[1]; }
    else       { V[0] = make_float4(0,0,0,0); V[1] = V[0]; }
    V[2] = q[2]; V[3] = q[3];
}

// slots j in [J0,13] correspond to x = (ox-1)*8 + j; interior J0=3, left edge J0=8
template <int J0>
__device__ __forceinline__ void count_row(const float4* Rv, const float4* Gv, const float4* Bv,
                                          unsigned long long& c64) {
#pragma unroll
    for (int j = J0; j <= 13; ++j) {
        float r = fget(Rv, j), g = fget(Gv, j), b = fget(Bv, j);
        float m = div3(r + g + b);
        int bin = (int)(m * 0.03125f);      // trunc(mean/32), exact pow2 scale
        c64 += 1ull << (bin << 3);
    }
}

template <int J0>
__device__ __forceinline__ void sum_row(const float4* Rv, const float4* Gv, const float4* Bv,
                                        int best, float& sr, float& sg, float& sb) {
#pragma unroll
    for (int j = J0; j <= 13; ++j) {
        float r = fget(Rv, j), g = fget(Gv, j), b = fget(Bv, j);
        float m = div3(r + g + b);
        int bin = (int)(m * 0.03125f);
        bool hit = (bin == best);
        sr += hit ? r : 0.0f;
        sg += hit ? g : 0.0f;
        sb += hit ? b : 0.0f;
    }
}

__global__ __launch_bounds__(256, 4)
void pixel_effect_kernel(const float* __restrict__ rgb, float* __restrict__ out) {
    int t    = blockIdx.x * 256 + threadIdx.x;
    int p    = t & 3;        // part within cell (quad lane)
    int cell = t >> 2;
    int ox   = cell & (OW - 1);
    int oy   = cell >> 8;

    const float* Rp = rgb;
    const float* Gp = rgb + HW;
    const float* Bp = rgb + 2 * HW;

    int  xbase = ox * 8 - 8;        // aligned 16-float span start (32B aligned)
    bool left  = (ox == 0);         // span starts OOB; only slots j>=8 valid
    int  ys    = oy * 8 - PAD;
    int  rb    = p * 3;             // first window-row index for this part
    int  nr    = (p < 3) ? 3 : 2;   // rows 0-2 / 3-5 / 6-8 / 9-10

    // ---- pass 1: packed byte counts ----
    unsigned long long c64 = 0;
#pragma unroll
    for (int k = 0; k < 3; ++k) {
        if (k >= nr) break;
        int y = ys + rb + k;        // max 2045, only top edge can be <0
        if (y >= 0) {
            int off = y * W + xbase;
            float4 Rv[4], Gv[4], Bv[4];
            load_row(Rp + off, Rv, left);
            load_row(Gp + off, Gv, left);
            load_row(Bp + off, Bv, left);
            if (left) count_row<8>(Rv, Gv, Bv, c64);
            else      count_row<3>(Rv, Gv, Bv, c64);
        }
    }
    // reduce across the quad (byte fields: max 121 < 256, no carries)
    c64 += __shfl_xor(c64, 1);
    c64 += __shfl_xor(c64, 2);

    // ---- argmax bin, first-max wins (matches jnp.argmax) ----
    unsigned lo = (unsigned)c64, hi = (unsigned)(c64 >> 32);
    int best = 0;
    unsigned bc = lo & 0xFFu;
#pragma unroll
    for (int b = 1; b < 8; ++b) {
        unsigned cb = ((b < 4 ? lo : hi) >> ((b & 3) * 8)) & 0xFFu;
        bool tt = cb > bc;
        bc   = tt ? cb : bc;
        best = tt ? b  : best;
    }

    // ---- pass 2: sum r,g,b of the winning bin (re-reads are L1/L2-hot) ----
    float sr = 0.0f, sg = 0.0f, sb = 0.0f;
#pragma unroll
    for (int k = 0; k < 3; ++k) {
        if (k >= nr) break;
        int y = ys + rb + k;
        if (y >= 0) {
            int off = y * W + xbase;
            float4 Rv[4], Gv[4], Bv[4];
            load_row(Rp + off, Rv, left);
            load_row(Gp + off, Gv, left);
            load_row(Bp + off, Bv, left);
            if (left) sum_row<8>(Rv, Gv, Bv, best, sr, sg, sb);
            else      sum_row<3>(Rv, Gv, Bv, best, sr, sg, sb);
        }
    }
    sr += __shfl_xor(sr, 1);  sr += __shfl_xor(sr, 2);
    sg += __shfl_xor(sg, 1);  sg += __shfl_xor(sg, 2);
    sb += __shfl_xor(sb, 1);  sb += __shfl_xor(sb, 2);

    float fbc = (float)bc;
    float orv = sr / fbc;
    float ogv = sg / fbc;
    float obv = sb / fbc;

    // ---- write: each part owns 2 rows of the 8x8 block, float4 x2 per row ----
    int    orow  = oy * 8 + p * 2;
    size_t sbase = (size_t)orow * W + (size_t)ox * 8;
    float vals[3] = { orv, ogv, obv };
#pragma unroll
    for (int c = 0; c < 3; ++c) {
        float  v  = vals[c];
        float4 vv = make_float4(v, v, v, v);
        float* o0 = out + (size_t)c * HW + sbase;
        ((float4*)o0)[0] = vv;  ((float4*)o0)[1] = vv;
        float* o1 = o0 + W;
        ((float4*)o1)[0] = vv;  ((float4*)o1)[1] = vv;
    }
}

extern "C" void kernel_launch(void* const* d_in, const int* in_sizes, int n_in,
                              void* d_out, int out_size, void* d_ws, size_t ws_size,
                              hipStream_t stream) {
    const float* rgb = (const float*)d_in[0];
    float* out = (float*)d_out;
    int total = OH * OW * 4;          // 4 threads per cell
    int block = 256;
    int grid  = total / block;        // 1024
    hipLaunchKernelGGL(pixel_effect_kernel, dim3(grid), dim3(block), 0, stream, rgb, out);
}

// Round 3
// 42.844 us; speedup vs baseline: 2.6131x; 2.6131x over previous
//
#include <hip/hip_runtime.h>

// PixelEffectModule: 8-bin intensity histogram over 11x11 windows at stride 8,
// argmax bin, output that bin's mean RGB, upsampled 8x8.
// Input: rgb (1,3,2048,2048) fp32 in [0,255). Output: (1,3,2048,2048) fp32.
//
// R3 structure: back to 1 thread/cell (R1's low-traffic mapping: 64 consecutive
// cells per wave = contiguous strips; R2's quad-split inflated fabric traffic
// 6x). VALU cuts: float4 loads, u64-packed counts, per-px bins cached as
// nibbles so pass 2 is bfe+cmp+3 fmac. Edge cells compile-time-templated and
// clustered into dedicated waves via variant-sorted cell ordering.

#define Wd 2048
#define Hd 2048
#define HW (Wd * Hd)

typedef unsigned int u32;
typedef unsigned long long u64;

// correctly-rounded t/3 (Markstein), 3 ops vs ~9-inst div expansion
__device__ __forceinline__ float div3(float t) {
    const float c = 0x1.555556p-2f;  // RN(1/3)
    float q0 = t * c;
    float r  = __builtin_fmaf(q0, -3.0f, t);
    return __builtin_fmaf(r, c, q0);
}

// NROWS: 11 interior / 6 top.  Slots j map to x = xbase + j; valid j in [J0,J1].
// Interior x: xbase = ox*8-8 (32B aligned), j in [3,13]. Left col: xbase=0, j in [0,5].
template <int NROWS, int J0, int J1>
__device__ __forceinline__ void process_cell(const float* __restrict__ rgb,
                                             float* __restrict__ out,
                                             int ox, int oy) {
    const float* Rp = rgb;
    const float* Gp = rgb + HW;
    const float* Bp = rgb + 2 * HW;
    const int NQ = (J1 <= 7) ? 2 : 4;           // float4 quads needed per row/ch
    int xbase = (J0 == 0) ? 0 : ox * 8 - 8;
    int y0    = (NROWS == 6) ? 0 : oy * 8 - 5;

    u32 rbl[NROWS], rbh[NROWS];                 // per-row packed bins (4b/px)
    u64 c64 = 0;                                // 8x u8 packed counts (max 121)

    // ---- pass 1: bin every pixel, pack counts + per-px bins ----
#pragma unroll
    for (int k = 0; k < NROWS; ++k) {
        int off = (y0 + k) * Wd + xbase;
        float vR[16], vG[16], vB[16];
#pragma unroll
        for (int q = 0; q < NQ; ++q) {
            *(float4*)(vR + 4 * q) = *(const float4*)(Rp + off + 4 * q);
            *(float4*)(vG + 4 * q) = *(const float4*)(Gp + off + 4 * q);
            *(float4*)(vB + 4 * q) = *(const float4*)(Bp + off + 4 * q);
        }
        u32 bl = 0, bh = 0;
#pragma unroll
        for (int j = J0; j <= J1; ++j) {
            float m = div3(vR[j] + vG[j] + vB[j]);
            u32 bin = (u32)(m * 0.03125f);      // trunc(mean/32), exact pow2
            c64 += 1ull << (bin << 3);
            int jj = j - J0;
            if (jj < 8) bl |= bin << (4 * jj);
            else        bh |= bin << (4 * (jj - 8));
        }
        rbl[k] = bl;
        rbh[k] = bh;
    }

    // ---- argmax bin, first-max wins (matches jnp.argmax) ----
    u32 lo = (u32)c64, hi = (u32)(c64 >> 32);
    u32 best = 0, bc = lo & 0xFFu;
#pragma unroll
    for (int b = 1; b < 8; ++b) {
        u32 cb = ((b < 4 ? lo : hi) >> ((b & 3) * 8)) & 0xFFu;
        bool t = cb > bc;
        bc   = t ? cb : bc;
        best = t ? (u32)b : best;
    }

    // ---- pass 2: reload (L1/L2-hot), sum winning bin via cached nibbles ----
    float sr = 0.f, sg = 0.f, sb = 0.f;
#pragma unroll
    for (int k = 0; k < NROWS; ++k) {
        int off = (y0 + k) * Wd + xbase;
        float vR[16], vG[16], vB[16];
#pragma unroll
        for (int q = 0; q < NQ; ++q) {
            *(float4*)(vR + 4 * q) = *(const float4*)(Rp + off + 4 * q);
            *(float4*)(vG + 4 * q) = *(const float4*)(Gp + off + 4 * q);
            *(float4*)(vB + 4 * q) = *(const float4*)(Bp + off + 4 * q);
        }
        u32 bl = rbl[k], bh = rbh[k];
#pragma unroll
        for (int j = J0; j <= J1; ++j) {
            int jj = j - J0;
            u32 bin = (jj < 8) ? ((bl >> (4 * jj)) & 7u)
                               : ((bh >> (4 * (jj - 8))) & 7u);
            float hm = (bin == best) ? 1.0f : 0.0f;
            sr = __builtin_fmaf(hm, vR[j], sr);
            sg = __builtin_fmaf(hm, vG[j], sg);
            sb = __builtin_fmaf(hm, vB[j], sb);
        }
    }

    float fbc = (float)bc;
    float orv = sr / fbc, ogv = sg / fbc, obv = sb / fbc;

    // ---- write 8x8 block per channel, 2x float4 per row ----
    size_t base = (size_t)(oy * 8) * Wd + (size_t)(ox * 8);
    float vals[3] = { orv, ogv, obv };
#pragma unroll
    for (int c = 0; c < 3; ++c) {
        float v = vals[c];
        float4 vv = make_float4(v, v, v, v);
        float* oc = out + (size_t)c * HW + base;
#pragma unroll
        for (int ry = 0; ry < 8; ++ry) {
            ((float4*)(oc + ry * Wd))[0] = vv;
            ((float4*)(oc + ry * Wd))[1] = vv;
        }
    }
}

__global__ __launch_bounds__(256)
void pixel_effect_kernel(const float* __restrict__ rgb, float* __restrict__ out) {
    int t = blockIdx.x * 256 + threadIdx.x;
    // variant-sorted cell ordering: interior (65025) | left col (255) |
    // top row (255) | corner (1). Only ~2 of 1025 waves mix variants.
    if (t < 65025) {
        u32 i = (u32)t;
        u32 q = (i + 1u + (i >> 8)) >> 8;   // i / 255 for i < 65280
        u32 r = i - q * 255u;
        process_cell<11, 3, 13>(rgb, out, 1 + (int)r, 1 + (int)q);
    } else if (t < 65280) {
        process_cell<11, 0, 5>(rgb, out, 0, t - 65025 + 1);   // left column
    } else if (t < 65535) {
        process_cell<6, 3, 13>(rgb, out, t - 65280 + 1, 0);   // top row
    } else {
        process_cell<6, 0, 5>(rgb, out, 0, 0);                // corner
    }
}

extern "C" void kernel_launch(void* const* d_in, const int* in_sizes, int n_in,
                              void* d_out, int out_size, void* d_ws, size_t ws_size,
                              hipStream_t stream) {
    const float* rgb = (const float*)d_in[0];
    float* out = (float*)d_out;
    int total = 256 * 256;            // 1 thread per cell
    int block = 256;
    int grid  = total / block;        // 256 workgroups -> 1 per CU
    hipLaunchKernelGGL(pixel_effect_kernel, dim3(grid), dim3(block), 0, stream, rgb, out);
}

// Round 4
// 37.220 us; speedup vs baseline: 3.0079x; 1.1511x over previous
//
#include <hip/hip_runtime.h>

// PixelEffectModule: 8-bin intensity histogram over 11x11 windows at stride 8,
// argmax bin, output that bin's mean RGB, upsampled 8x8.
// Input: rgb (1,3,2048,2048) fp32 in [0,255). Output: (1,3,2048,2048) fp32.
//
// R4: R3's traffic-proven mapping (wave = 64 consecutive cells) + 4x TLP.
// Each cell's 11 window rows split into 4 row-bands; band index lives in
// threadIdx.y = wave index (NOT lane bits -- R2 showed lane-scatter inflates
// fabric traffic 6x). 4 waves/SIMD hide load latency. LDS reduce across bands.

#define Wd 2048
#define Hd 2048
#define HW (Wd * Hd)

typedef unsigned int u32;
typedef unsigned long long u64;

// correctly-rounded t/3 (Markstein), 3 ops vs ~9-inst div expansion
__device__ __forceinline__ float div3(float t) {
    const float c = 0x1.555556p-2f;  // RN(1/3)
    float q0 = t * c;
    float r  = __builtin_fmaf(q0, -3.0f, t);
    return __builtin_fmaf(r, c, q0);
}

__global__ __launch_bounds__(256, 4)
void pixel_effect_kernel(const float* __restrict__ rgb, float* __restrict__ out) {
    const int lx = threadIdx.x;          // cell lane 0..63
    const int p  = threadIdx.y;          // row-band part 0..3 (= wave index)
    const int bx = blockIdx.x & 3;       // cell-column group
    const int oy = blockIdx.x >> 2;      // cell row
    const int ox = bx * 64 + lx;

    const float* Rp = rgb;
    const float* Gp = rgb + HW;
    const float* Bp = rgb + 2 * HW;

    // slot j maps x = xbase + j. Interior: xbase=8*(ox-1), valid j in [3,13].
    // ox==0: xbase=0, valid j in [0,5]. Loads (4 quads) always in bounds.
    const int xbase = (ox == 0) ? 0 : ox * 8 - 8;
    const u32 vmask = (ox == 0) ? 0x003Fu : 0x3FF8u;

    const int nr = (p < 3) ? 3 : 2;      // rows per band: 3/3/3/2
    const int rbase = p * 3;             // first window-row of this band
    const int ytop = oy * 8 - 5;

    __shared__ u64    sc[4][64];
    __shared__ float4 ss[4][64];

    // ---- pass 1: bin pixels of my band; packed byte counts + nibble cache ----
    u64 c64 = 0;
    u32 nbl[3], nbh[3];                  // per-row packed bins: j<8 / j>=8
#pragma unroll
    for (int k = 0; k < 3; ++k) {
        nbl[k] = 0; nbh[k] = 0;
        int y = ytop + rbase + k;        // wave-uniform
        if (k < nr && y >= 0) {
            int off = y * Wd + xbase;
            float vR[16], vG[16], vB[16];
#pragma unroll
            for (int q = 0; q < 4; ++q) {
                *(float4*)(vR + 4 * q) = *(const float4*)(Rp + off + 4 * q);
                *(float4*)(vG + 4 * q) = *(const float4*)(Gp + off + 4 * q);
                *(float4*)(vB + 4 * q) = *(const float4*)(Bp + off + 4 * q);
            }
            u32 bl = 0, bh = 0;
#pragma unroll
            for (int j = 0; j < 14; ++j) {
                float m = div3(vR[j] + vG[j] + vB[j]);
                u32 bin = (u32)(m * 0.03125f);         // trunc(mean/32)
                u64 valid = (vmask >> j) & 1u;
                c64 += valid << (bin << 3);
                if (j < 8) bl |= bin << (4 * j);
                else       bh |= bin << (4 * (j - 8));
            }
            nbl[k] = bl; nbh[k] = bh;
        }
    }
    sc[p][lx] = c64;
    __syncthreads();

    // ---- total counts + argmax (first-max wins, matches jnp.argmax) ----
    u64 tot = sc[0][lx] + sc[1][lx] + sc[2][lx] + sc[3][lx];  // bytes, max 121
    u32 lo = (u32)tot, hi = (u32)(tot >> 32);
    u32 best = 0, bc = lo & 0xFFu;
#pragma unroll
    for (int b = 1; b < 8; ++b) {
        u32 cb = ((b < 4 ? lo : hi) >> ((b & 3) * 8)) & 0xFFu;
        bool t = cb > bc;
        bc   = t ? cb : bc;
        best = t ? (u32)b : best;
    }

    // ---- pass 2: reload my band (L1/L2-hot), sum winning bin via nibbles ----
    float sr = 0.f, sg = 0.f, sb = 0.f;
#pragma unroll
    for (int k = 0; k < 3; ++k) {
        int y = ytop + rbase + k;
        if (k < nr && y >= 0) {
            int off = y * Wd + xbase;
            float vR[16], vG[16], vB[16];
#pragma unroll
            for (int q = 0; q < 4; ++q) {
                *(float4*)(vR + 4 * q) = *(const float4*)(Rp + off + 4 * q);
                *(float4*)(vG + 4 * q) = *(const float4*)(Gp + off + 4 * q);
                *(float4*)(vB + 4 * q) = *(const float4*)(Bp + off + 4 * q);
            }
            u32 bl = nbl[k], bh = nbh[k];
#pragma unroll
            for (int j = 0; j < 14; ++j) {
                u32 bin = ((j < 8) ? (bl >> (4 * j)) : (bh >> (4 * (j - 8)))) & 7u;
                bool hit = (((vmask >> j) & 1u) != 0u) && (bin == best);
                float hm = hit ? 1.0f : 0.0f;
                sr = __builtin_fmaf(hm, vR[j], sr);
                sg = __builtin_fmaf(hm, vG[j], sg);
                sb = __builtin_fmaf(hm, vB[j], sb);
            }
        }
    }
    ss[p][lx] = make_float4(sr, sg, sb, 0.0f);
    __syncthreads();

    float4 s0 = ss[0][lx], s1 = ss[1][lx], s2 = ss[2][lx], s3 = ss[3][lx];
    float fbc = (float)bc;
    float orv = (s0.x + s1.x + s2.x + s3.x) / fbc;
    float ogv = (s0.y + s1.y + s2.y + s3.y) / fbc;
    float obv = (s0.z + s1.z + s2.z + s3.z) / fbc;

    // ---- write: band p owns rows 2p, 2p+1 of the 8x8 block ----
    size_t base = (size_t)(oy * 8 + p * 2) * Wd + (size_t)(ox * 8);
    float vals[3] = { orv, ogv, obv };
#pragma unroll
    for (int c = 0; c < 3; ++c) {
        float v = vals[c];
        float4 vv = make_float4(v, v, v, v);
        float* o0 = out + (size_t)c * HW + base;
        ((float4*)o0)[0] = vv;  ((float4*)o0)[1] = vv;
        float* o1 = o0 + Wd;
        ((float4*)o1)[0] = vv;  ((float4*)o1)[1] = vv;
    }
}

extern "C" void kernel_launch(void* const* d_in, const int* in_sizes, int n_in,
                              void* d_out, int out_size, void* d_ws, size_t ws_size,
                              hipStream_t stream) {
    const float* rgb = (const float*)d_in[0];
    float* out = (float*)d_out;
    dim3 block(64, 4, 1);                 // 4 waves; tid.y = row-band = wave idx
    dim3 grid(4 * 256, 1, 1);             // (cell-col group, cell row) flattened
    hipLaunchKernelGGL(pixel_effect_kernel, grid, block, 0, stream, rgb, out);
}